// Round 5
// baseline (213.275 us; speedup 1.0000x reference)
//
#include <hip/hip_runtime.h>
#include <hip/hip_bf16.h>
#include <stdint.h>

#define NB 4
#define NT 4096
#define NE 100
#define ND 64

typedef __attribute__((ext_vector_type(8))) short short8;
typedef __attribute__((ext_vector_type(4))) short short4_;
typedef __attribute__((ext_vector_type(4))) float float4_;
typedef unsigned short ushort_t;

__device__ __forceinline__ unsigned short f2bf(float f) {
  union { float f; uint32_t u; } v; v.f = f;
  uint32_t u = v.u;
  u += 0x7fffu + ((u >> 16) & 1u);   // RNE
  return (unsigned short)(u >> 16);
}

__device__ __forceinline__ float bf2f(short us) {
  union { uint32_t u; float f; } v;
  v.u = ((uint32_t)(unsigned short)us) << 16;
  return v.f;
}

__device__ __forceinline__ float fast_exp2(float x) {
#if __has_builtin(__builtin_amdgcn_exp2f)
  return __builtin_amdgcn_exp2f(x);
#else
  return exp2f(x);
#endif
}

// ---------------- projection ----------------
// 256 blocks x 256 thr, 64 rows/block (W-staging amortized 4x vs R4).
// q = (x@Wq)*0.125*log2e, k = x@Wk, v^T via LDS transpose with 128B-contiguous
// per-d writes. Also zeroes the split-k ticket counters (block 0).
__global__ __launch_bounds__(256) void proj_kernel(
    const float* __restrict__ x, const float* __restrict__ Wq,
    const float* __restrict__ Wk, const float* __restrict__ Wv,
    ushort_t* __restrict__ Qb, ushort_t* __restrict__ Kb,
    ushort_t* __restrict__ Vt, int* __restrict__ cnt) {
  __shared__ __align__(16) float xs[64 * NE];          // 25.6 KB
  __shared__ __align__(16) ushort_t Wl[3][25][64][4];  // 38.4 KB
  __shared__ __align__(16) ushort_t Vl[64][72];        // 9.2 KB

  const int tid = threadIdx.x;
  const int r0  = blockIdx.x * 64;

  if (blockIdx.x == 0) { cnt[tid] = 0; cnt[tid + 256] = 0; }

  { // stage x[64][100] -> LDS, coalesced
    const float4_* xsrc = (const float4_*)(x + (size_t)r0 * NE);
    float4_* xdst = (float4_*)xs;
    for (int i = tid; i < 1600; i += 256) xdst[i] = xsrc[i];
  }
  { // stage W[3][100][64] -> LDS bf16, e-quad-major
    const int ch = tid >> 6, d = tid & 63;
    if (ch < 3) {
      const float* Ws = (ch == 0) ? Wq : (ch == 1) ? Wk : Wv;
      #pragma unroll 5
      for (int qd = 0; qd < 25; ++qd) {
        short4_ pk;
        #pragma unroll
        for (int jj = 0; jj < 4; ++jj)
          pk[jj] = (short)f2bf(Ws[(4*qd + jj)*ND + d]);
        *(short4_*)&Wl[ch][qd][d][0] = pk;
      }
    }
  }
  __syncthreads();

  const int wv = tid >> 6, lane = tid & 63;
  const float QS = 0.125f * 1.44269504088896340736f; // scale * log2(e)

  for (int it = 0; it < 4; ++it) {
    float aq[4] = {0,0,0,0}, ak[4] = {0,0,0,0}, av[4] = {0,0,0,0};
    const float* xw = xs + (it*16 + wv*4) * NE;
    for (int qd = 0; qd < 25; ++qd) {
      short4_ w4q = *(const short4_*)&Wl[0][qd][lane][0];
      short4_ w4k = *(const short4_*)&Wl[1][qd][lane][0];
      short4_ w4v = *(const short4_*)&Wl[2][qd][lane][0];
      float4_ x0 = *(const float4_*)&xw[0*NE + 4*qd];
      float4_ x1 = *(const float4_*)&xw[1*NE + 4*qd];
      float4_ x2 = *(const float4_*)&xw[2*NE + 4*qd];
      float4_ x3 = *(const float4_*)&xw[3*NE + 4*qd];
      #pragma unroll
      for (int jj = 0; jj < 4; ++jj) {
        float fq = bf2f(w4q[jj]), fk = bf2f(w4k[jj]), fv = bf2f(w4v[jj]);
        aq[0] += x0[jj]*fq; ak[0] += x0[jj]*fk; av[0] += x0[jj]*fv;
        aq[1] += x1[jj]*fq; ak[1] += x1[jj]*fk; av[1] += x1[jj]*fv;
        aq[2] += x2[jj]*fq; ak[2] += x2[jj]*fk; av[2] += x2[jj]*fv;
        aq[3] += x3[jj]*fq; ak[3] += x3[jj]*fk; av[3] += x3[jj]*fv;
      }
    }
    #pragma unroll
    for (int j = 0; j < 4; ++j) {
      int lrow = it*16 + wv*4 + j;
      int row  = r0 + lrow;
      Qb[(size_t)row*ND + lane] = f2bf(aq[j] * QS);
      Kb[(size_t)row*ND + lane] = f2bf(ak[j]);
      Vl[lrow][lane] = f2bf(av[j]);
    }
  }
  __syncthreads();

  { // transposed V write: per d, 64 t-values = 128B contiguous
    const int b = r0 >> 12, r0t = r0 & (NT - 1);
    for (int i = tid; i < 512; i += 256) {
      int d = i >> 3, seg = i & 7;
      short8 pk;
      #pragma unroll
      for (int k2 = 0; k2 < 8; ++k2) pk[k2] = (short)Vl[seg*8 + k2][d];
      *(short8*)(Vt + ((size_t)(b*ND + d))*NT + r0t + seg*8) = pk;
    }
  }
}

// ---------------- causal flash attention, split-K ----------------
// 1280 workers (2-wave blocks). Worker = (batch, 32-row q-group g, kv-slice s
// of <=16 tiles). nw(g) = (g+32)>>5 slices per group. Each worker: R4-style
// LDS-dbuf pipeline (wave0 stages K, wave1 stages V; XOR-swizzled), partial
// (m,l,O) online softmax. nw==1: write out directly. nw>1: write partials,
// atomic ticket; last worker combines (split-k fixup, no extra launch).
__global__ __launch_bounds__(128) void attn_kernel(
    const ushort_t* __restrict__ Qb, const ushort_t* __restrict__ Kb,
    const ushort_t* __restrict__ Vt, float* __restrict__ part,
    float* __restrict__ mlbuf, int* __restrict__ cnt,
    float* __restrict__ out) {
  __shared__ __align__(16) ushort_t Ks[2][64*64];
  __shared__ __align__(16) ushort_t Vs[2][64*64];
  __shared__ __align__(16) ushort_t Pbuf[2][16][72];
  __shared__ int isLast;

  const int tid  = threadIdx.x;
  const int w    = tid >> 6, lane = tid & 63;
  const int qrow = lane & 15, grp = lane >> 4;
  const int srow8 = lane >> 3, sc16 = lane & 7;

  const int wid = blockIdx.x;
  const int b   = wid / 320;
  const int u   = 319 - (wid - b*320);     // LPT: longest groups first
  int g, s;
  if (u < 32)       { g = u;                                s = 0; }
  else if (u < 96)  { int v = u - 32;              g = 32 + (v >> 1); s = v & 1; }
  else if (u < 192) { int v = u - 96; int q3 = v/3; g = 64 + q3;      s = v - 3*q3; }
  else              { int v = u - 192;             g = 96 + (v >> 2); s = v & 3; }

  const int nt = (g >> 1) + 1;          // total kv tiles for this group
  const int nw = (g + 32) >> 5;         // workers for this group
  const int t0 = s << 4;
  const int t1 = min(nt, t0 + 16);
  const int q0 = g << 5;
  const int qglob = q0 + 16*w + qrow;

  const ushort_t* Kbase = Kb + (size_t)b*NT*ND;
  const ushort_t* Vtb   = Vt + (size_t)b*ND*NT;

  const ushort_t* Qr = Qb + ((size_t)(b*NT + q0 + 16*w + qrow))*ND + 8*grp;
  const short8 qf0 = *(const short8*)(Qr);
  const short8 qf1 = *(const short8*)(Qr + 32);

  float4_ O0 = {0,0,0,0}, O1 = {0,0,0,0}, O2 = {0,0,0,0}, O3 = {0,0,0,0};
  float m = -1e30f, lsum = 0.f;
  short8 sr[8];

  { // prologue: stage tile t0
    const int kv0 = t0 << 6;
    #pragma unroll
    for (int i = 0; i < 8; ++i) {
      int row = 8*i + srow8;
      sr[i] = (w == 0)
        ? *(const short8*)(Kbase + (size_t)(kv0 + row)*ND + sc16*8)
        : *(const short8*)(Vtb + (size_t)row*NT + kv0 + sc16*8);
    }
    ushort_t* dst = (w == 0) ? Ks[0] : Vs[0];
    #pragma unroll
    for (int i = 0; i < 8; ++i) {
      int row = 8*i + srow8;
      *(short8*)&dst[row*64 + ((sc16 ^ (row & 7)) << 3)] = sr[i];
    }
  }
  __syncthreads();

  for (int t = t0; t < t1; ++t) {
    const int cur = (t - t0) & 1;
    const int kv0 = t << 6;

    if (t + 1 < t1) {  // issue next tile's global loads EARLY
      const int kn0 = kv0 + 64;
      #pragma unroll
      for (int i = 0; i < 8; ++i) {
        int row = 8*i + srow8;
        sr[i] = (w == 0)
          ? *(const short8*)(Kbase + (size_t)(kn0 + row)*ND + sc16*8)
          : *(const short8*)(Vtb + (size_t)row*NT + kn0 + sc16*8);
      }
    }

    const ushort_t* Kc = Ks[cur];
    const ushort_t* Vc = Vs[cur];

    // S^T = K_tile . Q^T  (lane owns q-row qglob; kv = kv0+st*16+grp*4+r)
    float4_ sA[4];
    #pragma unroll
    for (int st = 0; st < 4; ++st) {
      int row = st*16 + qrow;
      short8 kf0 = *(const short8*)&Kc[row*64 + (((grp    ) ^ (row & 7)) << 3)];
      short8 kf1 = *(const short8*)&Kc[row*64 + (((grp + 4) ^ (row & 7)) << 3)];
      float4_ acc = {0,0,0,0};
      acc = __builtin_amdgcn_mfma_f32_16x16x32_bf16(kf0, qf0, acc, 0,0,0);
      acc = __builtin_amdgcn_mfma_f32_16x16x32_bf16(kf1, qf1, acc, 0,0,0);
      sA[st] = acc;
    }

    // V fragments early: latency hides under softmax
    short8 vf[8];
    #pragma unroll
    for (int j = 0; j < 4; ++j) {
      int row = j*16 + qrow;
      vf[2*j]   = *(const short8*)&Vc[row*64 + (((grp    ) ^ (row & 7)) << 3)];
      vf[2*j+1] = *(const short8*)&Vc[row*64 + (((grp + 4) ^ (row & 7)) << 3)];
    }

    if (t == nt - 1) { // only the globally-last tile violates causality
      #pragma unroll
      for (int st = 0; st < 4; ++st)
        #pragma unroll
        for (int r = 0; r < 4; ++r) {
          int kv = kv0 + st*16 + grp*4 + r;
          if (kv > qglob) sA[st][r] = -1e30f;
        }
    }

    // online softmax (log2 domain), defer-max THR=8
    float pmax = sA[0][0];
    #pragma unroll
    for (int st = 0; st < 4; ++st)
      #pragma unroll
      for (int r = 0; r < 4; ++r) pmax = fmaxf(pmax, sA[st][r]);
    if (!__all(pmax <= m + 8.0f)) {
      float tm = pmax;
      tm = fmaxf(tm, __shfl_xor(tm, 16));
      tm = fmaxf(tm, __shfl_xor(tm, 32));
      const float mnew  = fmaxf(m, tm);
      const float alpha = fast_exp2(m - mnew);
      m = mnew;
      lsum *= alpha;
      #pragma unroll
      for (int r = 0; r < 4; ++r) {
        float ar = __shfl(alpha, grp*4 + r);
        O0[r] *= ar; O1[r] *= ar; O2[r] *= ar; O3[r] *= ar;
      }
    }

    float psum = 0.f;
    #pragma unroll
    for (int st = 0; st < 4; ++st) {
      short4_ pv;
      #pragma unroll
      for (int r = 0; r < 4; ++r) {
        float p = fast_exp2(sA[st][r] - m);
        psum += p;
        pv[r] = (short)f2bf(p);
      }
      *(short4_*)&Pbuf[w][qrow][st*16 + grp*4] = pv;
    }
    psum += __shfl_xor(psum, 16);
    psum += __shfl_xor(psum, 32);
    lsum += psum;

    asm volatile("s_waitcnt lgkmcnt(0)" ::: "memory");

    const short8 pf0 = *(const short8*)&Pbuf[w][qrow][8*grp];
    const short8 pf1 = *(const short8*)&Pbuf[w][qrow][32 + 8*grp];
    O0 = __builtin_amdgcn_mfma_f32_16x16x32_bf16(pf0, vf[0], O0, 0,0,0);
    O0 = __builtin_amdgcn_mfma_f32_16x16x32_bf16(pf1, vf[1], O0, 0,0,0);
    O1 = __builtin_amdgcn_mfma_f32_16x16x32_bf16(pf0, vf[2], O1, 0,0,0);
    O1 = __builtin_amdgcn_mfma_f32_16x16x32_bf16(pf1, vf[3], O1, 0,0,0);
    O2 = __builtin_amdgcn_mfma_f32_16x16x32_bf16(pf0, vf[4], O2, 0,0,0);
    O2 = __builtin_amdgcn_mfma_f32_16x16x32_bf16(pf1, vf[5], O2, 0,0,0);
    O3 = __builtin_amdgcn_mfma_f32_16x16x32_bf16(pf0, vf[6], O3, 0,0,0);
    O3 = __builtin_amdgcn_mfma_f32_16x16x32_bf16(pf1, vf[7], O3, 0,0,0);

    if (t + 1 < t1) {  // ds_write staged regs LATE into the other buffer
      ushort_t* dst = (w == 0) ? Ks[cur ^ 1] : Vs[cur ^ 1];
      #pragma unroll
      for (int i = 0; i < 8; ++i) {
        int row = 8*i + srow8;
        *(short8*)&dst[row*64 + ((sc16 ^ (row & 7)) << 3)] = sr[i];
      }
    }
    __syncthreads();
  }

  if (nw == 1) {
    // single worker: normalize and write out directly
    float* orow = out + ((size_t)(b*NT + q0 + 16*w)) * ND;
    #pragma unroll
    for (int r = 0; r < 4; ++r) {
      float inv = 1.f / __shfl(lsum, grp*4 + r);
      int qr = grp*4 + r;
      orow[qr*ND + 0*16 + qrow] = O0[r]*inv;
      orow[qr*ND + 1*16 + qrow] = O1[r]*inv;
      orow[qr*ND + 2*16 + qrow] = O2[r]*inv;
      orow[qr*ND + 3*16 + qrow] = O3[r]*inv;
    }
  } else {
    const int gi = b*128 + g;
    float* Op  = part  + ((size_t)gi*4 + s)*2048;   // [32][64]
    float* Mlp = mlbuf + ((size_t)gi*4 + s)*64;     // [32][2]
    #pragma unroll
    for (int r = 0; r < 4; ++r) {
      int row = 16*w + grp*4 + r;
      Op[row*64 + 0*16 + qrow] = O0[r];
      Op[row*64 + 1*16 + qrow] = O1[r];
      Op[row*64 + 2*16 + qrow] = O2[r];
      Op[row*64 + 3*16 + qrow] = O3[r];
    }
    if (lane < 16) { Mlp[(16*w + lane)*2] = m; Mlp[(16*w + lane)*2 + 1] = lsum; }
    __syncthreads();
    if (tid == 0) {
      __threadfence();
      int old = atomicAdd(&cnt[gi], 1);
      isLast = (old == nw - 1) ? 1 : 0;
    }
    __syncthreads();
    if (isLast) {
      __threadfence();
      const float* Pp = part  + (size_t)gi*4*2048;
      const float* Mp = mlbuf + (size_t)gi*4*64;
      for (int i = tid; i < 2048; i += 128) {
        int row = i >> 6, d = i & 63;
        float M = -1e30f;
        for (int s2 = 0; s2 < nw; ++s2) M = fmaxf(M, Mp[s2*64 + row*2]);
        float ls = 0.f, o = 0.f;
        for (int s2 = 0; s2 < nw; ++s2) {
          float sc = fast_exp2(Mp[s2*64 + row*2] - M);
          ls += sc * Mp[s2*64 + row*2 + 1];
          o  += sc * Pp[(size_t)s2*2048 + row*64 + d];
        }
        out[((size_t)b*NT + q0 + row)*ND + d] = o / ls;
      }
    }
  }
}

extern "C" void kernel_launch(void* const* d_in, const int* in_sizes, int n_in,
                              void* d_out, int out_size, void* d_ws, size_t ws_size,
                              hipStream_t stream) {
  const float* x  = (const float*)d_in[0];
  const float* Wq = (const float*)d_in[1];
  const float* Wk = (const float*)d_in[2];
  const float* Wv = (const float*)d_in[3];
  float* out = (float*)d_out;

  char* ws = (char*)d_ws;
  ushort_t* Qb   = (ushort_t*)(ws);                        // 2 MB
  ushort_t* Kb   = (ushort_t*)(ws + (2u<<20));             // 2 MB
  ushort_t* Vt   = (ushort_t*)(ws + (4u<<20));             // 2 MB
  float*    part = (float*)(ws + (6u<<20));                // 16 MB
  float*    mlb  = (float*)(ws + (22u<<20));               // 512 KB
  int*      cnt  = (int*)(ws + (22u<<20) + (512u<<10));    // 2 KB

  proj_kernel<<<dim3(256), dim3(256), 0, stream>>>(x, Wq, Wk, Wv, Qb, Kb, Vt, cnt);
  attn_kernel<<<dim3(NB*320), dim3(128), 0, stream>>>(Qb, Kb, Vt, part, mlb, cnt, out);
}

// Round 6
// 124.852 us; speedup vs baseline: 1.7082x; 1.7082x over previous
//
#include <hip/hip_runtime.h>
#include <hip/hip_bf16.h>
#include <stdint.h>

#define NB 4
#define NT 4096
#define NE 100
#define ND 64

typedef __attribute__((ext_vector_type(8))) short short8;
typedef __attribute__((ext_vector_type(4))) short short4_;
typedef __attribute__((ext_vector_type(4))) float float4_;
typedef unsigned short ushort_t;

__device__ __forceinline__ unsigned short f2bf(float f) {
  union { float f; uint32_t u; } v; v.f = f;
  uint32_t u = v.u;
  u += 0x7fffu + ((u >> 16) & 1u);   // RNE
  return (unsigned short)(u >> 16);
}

__device__ __forceinline__ float bf2f(short us) {
  union { uint32_t u; float f; } v;
  v.u = ((uint32_t)(unsigned short)us) << 16;
  return v.f;
}

__device__ __forceinline__ float fast_exp2(float x) {
#if __has_builtin(__builtin_amdgcn_exp2f)
  return __builtin_amdgcn_exp2f(x);
#else
  return exp2f(x);
#endif
}

// ---------------- projection ----------------
// 256 blocks x 256 thr, 64 rows/block. q = (x@Wq)*0.125*log2e, k = x@Wk,
// v^T via LDS transpose with 128B-contiguous per-d writes. W staged once
// per block into LDS bf16.
__global__ __launch_bounds__(256) void proj_kernel(
    const float* __restrict__ x, const float* __restrict__ Wq,
    const float* __restrict__ Wk, const float* __restrict__ Wv,
    ushort_t* __restrict__ Qb, ushort_t* __restrict__ Kb,
    ushort_t* __restrict__ Vt) {
  __shared__ __align__(16) float xs[64 * NE];          // 25.6 KB
  __shared__ __align__(16) ushort_t Wl[3][25][64][4];  // 38.4 KB
  __shared__ __align__(16) ushort_t Vl[64][72];        // 9.2 KB

  const int tid = threadIdx.x;
  const int r0  = blockIdx.x * 64;

  { // stage x[64][100] -> LDS, coalesced
    const float4_* xsrc = (const float4_*)(x + (size_t)r0 * NE);
    float4_* xdst = (float4_*)xs;
    for (int i = tid; i < 1600; i += 256) xdst[i] = xsrc[i];
  }
  { // stage W[3][100][64] -> LDS bf16, e-quad-major
    const int ch = tid >> 6, d = tid & 63;
    if (ch < 3) {
      const float* Ws = (ch == 0) ? Wq : (ch == 1) ? Wk : Wv;
      #pragma unroll 5
      for (int qd = 0; qd < 25; ++qd) {
        short4_ pk;
        #pragma unroll
        for (int jj = 0; jj < 4; ++jj)
          pk[jj] = (short)f2bf(Ws[(4*qd + jj)*ND + d]);
        *(short4_*)&Wl[ch][qd][d][0] = pk;
      }
    }
  }
  __syncthreads();

  const int wv = tid >> 6, lane = tid & 63;
  const float QS = 0.125f * 1.44269504088896340736f; // scale * log2(e)

  for (int it = 0; it < 4; ++it) {
    float aq[4] = {0,0,0,0}, ak[4] = {0,0,0,0}, av[4] = {0,0,0,0};
    const float* xw = xs + (it*16 + wv*4) * NE;
    for (int qd = 0; qd < 25; ++qd) {
      short4_ w4q = *(const short4_*)&Wl[0][qd][lane][0];
      short4_ w4k = *(const short4_*)&Wl[1][qd][lane][0];
      short4_ w4v = *(const short4_*)&Wl[2][qd][lane][0];
      float4_ x0 = *(const float4_*)&xw[0*NE + 4*qd];
      float4_ x1 = *(const float4_*)&xw[1*NE + 4*qd];
      float4_ x2 = *(const float4_*)&xw[2*NE + 4*qd];
      float4_ x3 = *(const float4_*)&xw[3*NE + 4*qd];
      #pragma unroll
      for (int jj = 0; jj < 4; ++jj) {
        float fq = bf2f(w4q[jj]), fk = bf2f(w4k[jj]), fv = bf2f(w4v[jj]);
        aq[0] += x0[jj]*fq; ak[0] += x0[jj]*fk; av[0] += x0[jj]*fv;
        aq[1] += x1[jj]*fq; ak[1] += x1[jj]*fk; av[1] += x1[jj]*fv;
        aq[2] += x2[jj]*fq; ak[2] += x2[jj]*fk; av[2] += x2[jj]*fv;
        aq[3] += x3[jj]*fq; ak[3] += x3[jj]*fk; av[3] += x3[jj]*fv;
      }
    }
    #pragma unroll
    for (int j = 0; j < 4; ++j) {
      int lrow = it*16 + wv*4 + j;
      int row  = r0 + lrow;
      Qb[(size_t)row*ND + lane] = f2bf(aq[j] * QS);
      Kb[(size_t)row*ND + lane] = f2bf(ak[j]);
      Vl[lrow][lane] = f2bf(av[j]);
    }
  }
  __syncthreads();

  { // transposed V write: per d, 64 t-values = 128B contiguous
    const int b = r0 >> 12, r0t = r0 & (NT - 1);
    for (int i = tid; i < 512; i += 256) {
      int d = i >> 3, seg = i & 7;
      short8 pk;
      #pragma unroll
      for (int k2 = 0; k2 < 8; ++k2) pk[k2] = (short)Vl[seg*8 + k2][d];
      *(short8*)(Vt + ((size_t)(b*ND + d))*NT + r0t + seg*8) = pk;
    }
  }
}

// ---------------- causal flash attention ----------------
// 256 blocks x 512 thr (8 waves = 4 wave-pairs), 1 block/CU, XCD-mapped:
// blk&7 = xcd, batch = xcd>>1 -> each XCD's L2 holds one batch's K+Vt (2MB).
// Block owns pair of 32-row q-groups (127-p, p) = 65 kv-tiles total.
// Per phase, the 4 wave-pairs take kv tiles strided by 4; each pair runs the
// R4 dbuf pipeline (h=0 stages K, h=1 stages V; XOR-swizzle; issue-early /
// ds_write-late). Per-pair (m,l,O) partials combined in-LDS (arena aliasing).
__global__ __launch_bounds__(512) void attn_kernel(
    const ushort_t* __restrict__ Qb, const ushort_t* __restrict__ Kb,
    const ushort_t* __restrict__ Vt, float* __restrict__ out) {
  extern __shared__ __align__(16) char arena[];
  ushort_t* KsB = (ushort_t*)arena;          // [4 pairs][2 buf][4096]
  ushort_t* VsB = KsB + 4*2*4096;            // [4 pairs][2 buf][4096]
  ushort_t* PbB = VsB + 4*2*4096;            // [8 waves][16*72]
  float*    Om  = (float*)arena;             // alias: [8 waves][16*64]
  float*    Ml  = (float*)(arena + 131072);  // alias: [8 waves][16][2]

  const int tid  = threadIdx.x;
  const int w    = tid >> 6, lane = tid & 63;
  const int pp   = w >> 1, h = w & 1;        // wave-pair, half
  const int qrow = lane & 15, grp = lane >> 4;
  const int srow8 = lane >> 3, sc16 = lane & 7;

  const int blk = blockIdx.x;
  const int xcd = blk & 7;
  const int b   = xcd >> 1;                       // batch pinned to XCD pair
  const int p   = ((blk >> 3) << 1) | (xcd & 1);  // pair id [0,64)

  const ushort_t* Kbase = Kb + (size_t)b*NT*ND;
  const ushort_t* Vtb   = Vt + (size_t)b*ND*NT;

  ushort_t* Ks0 = KsB + pp*8192;   // this pair's K double-buffer
  ushort_t* Vs0 = VsB + pp*8192;
  ushort_t* Pw  = PbB + w*1152;    // this wave's P buffer [16][72]

  for (int phase = 0; phase < 2; ++phase) {
    const int g  = phase ? p : (127 - p);
    const int q0 = g << 5;
    const int nt = (g >> 1) + 1;
    const int qglob = q0 + h*16 + qrow;

    const ushort_t* Qr = Qb + ((size_t)(b*NT + q0 + h*16 + qrow))*ND + 8*grp;
    const short8 qf0 = *(const short8*)(Qr);
    const short8 qf1 = *(const short8*)(Qr + 32);

    float4_ O0 = {0,0,0,0}, O1 = {0,0,0,0}, O2 = {0,0,0,0}, O3 = {0,0,0,0};
    float m = -1e30f, lsum = 0.f;
    short8 sr[8];

    const int maxIter = (nt + 3) >> 2;

    if (pp < nt) {  // prologue: stage tile pp into buf 0
      const int kv0 = pp << 6;
      #pragma unroll
      for (int i = 0; i < 8; ++i) {
        int row = 8*i + srow8;
        sr[i] = (h == 0)
          ? *(const short8*)(Kbase + (size_t)(kv0 + row)*ND + sc16*8)
          : *(const short8*)(Vtb + (size_t)row*NT + kv0 + sc16*8);
      }
      ushort_t* dst = (h == 0) ? Ks0 : Vs0;
      #pragma unroll
      for (int i = 0; i < 8; ++i) {
        int row = 8*i + srow8;
        *(short8*)&dst[row*64 + ((sc16 ^ (row & 7)) << 3)] = sr[i];
      }
    }
    __syncthreads();

    for (int it = 0; it < maxIter; ++it) {
      const int t    = pp + (it << 2);
      const int buf  = it & 1;
      const bool act = (t < nt);
      const bool hasNext = act && (t + 4 < nt);

      if (hasNext) {  // issue next tile's global loads EARLY
        const int kn0 = (t + 4) << 6;
        #pragma unroll
        for (int i = 0; i < 8; ++i) {
          int row = 8*i + srow8;
          sr[i] = (h == 0)
            ? *(const short8*)(Kbase + (size_t)(kn0 + row)*ND + sc16*8)
            : *(const short8*)(Vtb + (size_t)row*NT + kn0 + sc16*8);
        }
      }

      if (act) {
        const int kv0 = t << 6;
        const ushort_t* Kc = Ks0 + buf*4096;
        const ushort_t* Vc = Vs0 + buf*4096;

        // S^T = K_tile . Q^T (lane owns q-row qglob; kv = kv0+st*16+grp*4+r)
        float4_ sA[4];
        #pragma unroll
        for (int st = 0; st < 4; ++st) {
          int row = st*16 + qrow;
          short8 kf0 = *(const short8*)&Kc[row*64 + (((grp    ) ^ (row & 7)) << 3)];
          short8 kf1 = *(const short8*)&Kc[row*64 + (((grp + 4) ^ (row & 7)) << 3)];
          float4_ acc = {0,0,0,0};
          acc = __builtin_amdgcn_mfma_f32_16x16x32_bf16(kf0, qf0, acc, 0,0,0);
          acc = __builtin_amdgcn_mfma_f32_16x16x32_bf16(kf1, qf1, acc, 0,0,0);
          sA[st] = acc;
        }

        // V fragments early: latency hides under softmax
        short8 vf[8];
        #pragma unroll
        for (int j = 0; j < 4; ++j) {
          int row = j*16 + qrow;
          vf[2*j]   = *(const short8*)&Vc[row*64 + (((grp    ) ^ (row & 7)) << 3)];
          vf[2*j+1] = *(const short8*)&Vc[row*64 + (((grp + 4) ^ (row & 7)) << 3)];
        }

        if (t == nt - 1) { // only the diagonal tile violates causality
          #pragma unroll
          for (int st = 0; st < 4; ++st)
            #pragma unroll
            for (int r = 0; r < 4; ++r) {
              int kv = kv0 + st*16 + grp*4 + r;
              if (kv > qglob) sA[st][r] = -1e30f;
            }
        }

        // online softmax (log2 domain), defer-max THR=8
        float pmax = sA[0][0];
        #pragma unroll
        for (int st = 0; st < 4; ++st)
          #pragma unroll
          for (int r = 0; r < 4; ++r) pmax = fmaxf(pmax, sA[st][r]);
        if (!__all(pmax <= m + 8.0f)) {
          float tm = pmax;
          tm = fmaxf(tm, __shfl_xor(tm, 16));
          tm = fmaxf(tm, __shfl_xor(tm, 32));
          const float mnew  = fmaxf(m, tm);
          const float alpha = fast_exp2(m - mnew);
          m = mnew;
          lsum *= alpha;
          #pragma unroll
          for (int r = 0; r < 4; ++r) {
            float ar = __shfl(alpha, grp*4 + r);
            O0[r] *= ar; O1[r] *= ar; O2[r] *= ar; O3[r] *= ar;
          }
        }

        float psum = 0.f;
        #pragma unroll
        for (int st = 0; st < 4; ++st) {
          short4_ pv;
          #pragma unroll
          for (int r = 0; r < 4; ++r) {
            float pe = fast_exp2(sA[st][r] - m);
            psum += pe;
            pv[r] = (short)f2bf(pe);
          }
          *(short4_*)&Pw[qrow*72 + st*16 + grp*4] = pv;
        }
        psum += __shfl_xor(psum, 16);
        psum += __shfl_xor(psum, 32);
        lsum += psum;

        asm volatile("s_waitcnt lgkmcnt(0)" ::: "memory");

        const short8 pf0 = *(const short8*)&Pw[qrow*72 + 8*grp];
        const short8 pf1 = *(const short8*)&Pw[qrow*72 + 32 + 8*grp];
        O0 = __builtin_amdgcn_mfma_f32_16x16x32_bf16(pf0, vf[0], O0, 0,0,0);
        O0 = __builtin_amdgcn_mfma_f32_16x16x32_bf16(pf1, vf[1], O0, 0,0,0);
        O1 = __builtin_amdgcn_mfma_f32_16x16x32_bf16(pf0, vf[2], O1, 0,0,0);
        O1 = __builtin_amdgcn_mfma_f32_16x16x32_bf16(pf1, vf[3], O1, 0,0,0);
        O2 = __builtin_amdgcn_mfma_f32_16x16x32_bf16(pf0, vf[4], O2, 0,0,0);
        O2 = __builtin_amdgcn_mfma_f32_16x16x32_bf16(pf1, vf[5], O2, 0,0,0);
        O3 = __builtin_amdgcn_mfma_f32_16x16x32_bf16(pf0, vf[6], O3, 0,0,0);
        O3 = __builtin_amdgcn_mfma_f32_16x16x32_bf16(pf1, vf[7], O3, 0,0,0);
      }

      if (hasNext) {  // ds_write staged regs LATE into the other buffer
        ushort_t* dst = ((h == 0) ? Ks0 : Vs0) + (buf ^ 1)*4096;
        #pragma unroll
        for (int i = 0; i < 8; ++i) {
          int row = 8*i + srow8;
          *(short8*)&dst[row*64 + ((sc16 ^ (row & 7)) << 3)] = sr[i];
        }
      }
      __syncthreads();
    }

    // ---- per-wave partials into arena (aliases Ks/Vs — loop is done)
    #pragma unroll
    for (int r = 0; r < 4; ++r) {
      int row = grp*4 + r;
      Om[w*1024 + row*64 + 0*16 + qrow] = O0[r];
      Om[w*1024 + row*64 + 1*16 + qrow] = O1[r];
      Om[w*1024 + row*64 + 2*16 + qrow] = O2[r];
      Om[w*1024 + row*64 + 3*16 + qrow] = O3[r];
    }
    if (lane < 16) {
      Ml[(w*16 + lane)*2]     = m;
      Ml[(w*16 + lane)*2 + 1] = lsum;
    }
    __syncthreads();

    // ---- combine the 4 pair-partials, normalize, store
    for (int i = tid; i < 2048; i += 512) {
      int row = i >> 6, d = i & 63;
      int hh = row >> 4, r16 = row & 15;
      float M = -3e30f;
      #pragma unroll
      for (int p2 = 0; p2 < 4; ++p2)
        M = fmaxf(M, Ml[((2*p2 + hh)*16 + r16)*2]);
      float ls = 0.f, os = 0.f;
      #pragma unroll
      for (int p2 = 0; p2 < 4; ++p2) {
        int w2 = 2*p2 + hh;
        float sc = fast_exp2(Ml[(w2*16 + r16)*2] - M);
        ls += sc * Ml[(w2*16 + r16)*2 + 1];
        os += sc * Om[w2*1024 + r16*64 + d];
      }
      out[((size_t)b*NT + q0 + row)*ND + d] = os / ls;
    }
    __syncthreads();   // arena safe to reuse in next phase
  }
}

extern "C" void kernel_launch(void* const* d_in, const int* in_sizes, int n_in,
                              void* d_out, int out_size, void* d_ws, size_t ws_size,
                              hipStream_t stream) {
  const float* x  = (const float*)d_in[0];
  const float* Wq = (const float*)d_in[1];
  const float* Wk = (const float*)d_in[2];
  const float* Wv = (const float*)d_in[3];
  float* out = (float*)d_out;

  ushort_t* Qb = (ushort_t*)d_ws;                 // [B][T][64] bf16, 2 MB
  ushort_t* Kb = Qb + (size_t)NB*NT*ND;           // [B][T][64] bf16, 2 MB
  ushort_t* Vt = Kb + (size_t)NB*NT*ND;           // [B][64][T] bf16, 2 MB

  const int ldsBytes = (4*2*4096 + 4*2*4096 + 8*16*72) * 2;  // 149504 B
  static bool attrSet = false;  // idempotent host-side attribute (not a stream op)
  (void)attrSet;
  hipFuncSetAttribute((const void*)attn_kernel,
                      hipFuncAttributeMaxDynamicSharedMemorySize, ldsBytes);

  proj_kernel<<<dim3(256), dim3(256), 0, stream>>>(x, Wq, Wk, Wv, Qb, Kb, Vt);
  attn_kernel<<<dim3(256), dim3(512), ldsBytes, stream>>>(Qb, Kb, Vt, out);
}